// Round 9
// baseline (162.139 us; speedup 1.0000x reference)
//
#include <hip/hip_runtime.h>

#define DEV __device__ __forceinline__

typedef __attribute__((ext_vector_type(8))) short short8v;
typedef __attribute__((ext_vector_type(4))) float f32x4;
typedef __attribute__((ext_vector_type(4))) int int4v;

DEV unsigned short bfr(float f) {                 // fp32 -> bf16 RNE (weights)
    unsigned u = __float_as_uint(f);
    return (unsigned short)((u + 0x7fffu + ((u >> 16) & 1u)) >> 16);
}
DEV short bft(float f) { return (short)(__float_as_uint(f) >> 16); } // truncate (activations)
DEV float bf2f(unsigned short h) { return __uint_as_float(((unsigned)h) << 16); }
DEV float frcp(float x) { return __builtin_amdgcn_rcpf(x); }
DEV float ftanh(float x) { float e = __expf(2.0f * x); return 1.0f - 2.0f * frcp(e + 1.0f); }

// pack two f32 into one u32 of 2x bf16 (truncate) via v_perm_b32:
// D = {hi16(a) : hi16(b)}  (a -> high short, b -> low short)
DEV int pk2(float a, float b) {
    return (int)__builtin_amdgcn_perm(__float_as_uint(a), __float_as_uint(b), 0x07060302u);
}

constexpr int NN = 4096, TT = 128, RING = 32;
#define MFMA32(a, b, c) __builtin_amdgcn_mfma_f32_16x16x32_bf16(a, b, c, 0, 0, 0)

// Lock-free producer/consumer, 512 threads. R8 POST-MORTEM: fake-dep was
// dodged by reordering (odd-group -> red1 -> even-group -> red0); VGPR
// pinned at 88 across SIX scheduling attacks. The compiler ALWAYS emits
// {8 MFMA, VALU, 8 MFMA, VALU}. THIS ROUND: accept that shape and make it
// cheap -- reduction-free step via B-side folding (R7's refchecked math,
// WITHOUT R7's serializing C-chains):
//    tmp'_j = sum_d (A_d^T (ev_d*tmp))_j
//  - B_d = bf16(ev_d*tmpf) prepped upfront (96 VALU ~ 192cyc, off MFMA path)
//  - 16 INDEPENDENT MFMAs (the structure the compiler already prefers)
//  - d-sum = plain f32 partial sums of accs (56 adds ~ 112cyc) -- the
//    "between-groups" VALU shrinks from 64 ev-weighted fmaf to ~24 adds,
//    which fits inside the latency shadow; the 8+8 split becomes ~free.
// Predicted step ~750cyc vs 1194 measured (R4 model, held to ~3%).
// R1-R3 LESSON: 512 threads only (1024 => 64-VGPR cap => spills).
// R2 LESSON: no asm memory clobbers in hot loops. R6 base kept: publish/4,
// poll/8, wave-4 idle, LDS pad >80KB (1 blk/CU => 256-VGPR budget).

__global__ __launch_bounds__(512) __attribute__((amdgpu_waves_per_eu(2)))
void wfa_kernel(
    const float* __restrict__ x,
    const float* __restrict__ e1w, const float* __restrict__ e1b,
    const float* __restrict__ e2w, const float* __restrict__ e2b,
    const float* __restrict__ A,
    const float* __restrict__ initw,
    const float* __restrict__ n1w, const float* __restrict__ n1b,
    const float* __restrict__ n2w, const float* __restrict__ n2b,
    const float* __restrict__ muw, const float* __restrict__ mub,
    const float* __restrict__ sgw, const float* __restrict__ sgb,
    const float* __restrict__ alw, const float* __restrict__ alb,
    float* __restrict__ out)
{
    __shared__ __align__(16) unsigned short enc_l[TT * 128];  // [t][n*8+d] bf16, 32KB
    __shared__ __align__(16) float x_l[16 * 130];             // [n][t]
    __shared__ __align__(16) short8v ring_l[RING][64];        // tmp frags, 32KB
    __shared__ __align__(16) float n1b_l[64], n2b_l[64], hb_l[48];
    __shared__ float part_l[8][16];
    __shared__ float pad_l[2048];   // 8KB pad: LDS >80KB => 1 blk/CU
                                    // => 256-VGPR budget headroom
    __shared__ int head_l;     // items published by scanner
    __shared__ int ticket_l;   // next item index to hand out
    __shared__ int prog_l[7];  // per-consumer: all my ring reads < prog are done

    const int tid = threadIdx.x;
    const int wv = tid >> 6, lane = tid & 63;
    const int quad = lane >> 4, col = lane & 15;
    const int n0 = blockIdx.x * 16;
    const f32x4 z4 = {0.f, 0.f, 0.f, 0.f};

    // ---- stage x + biases + control ----
    for (int i = tid; i < 16 * TT; i += 512)
        x_l[(i >> 7) * 130 + (i & 127)] = x[(n0 + (i >> 7)) * TT + (i & 127)];
    if (tid < 64) { n1b_l[tid] = n1b[tid]; n2b_l[tid] = n2b[tid]; }
    if (tid >= 64 && tid < 112) {
        const int i = tid - 64, mt = i >> 4, k = i & 15;
        hb_l[i] = (k < 10) ? ((mt == 0) ? mub[k] : (mt == 1) ? sgb[k] : alb[k]) : 0.f;
    }
    // prog slot 3 belongs to wave 4, which is idled: park at +inf
    if (tid >= 112 && tid < 119) prog_l[tid - 112] = (tid == 115) ? (1 << 30) : 0;
    if (tid == 120) { head_l = 0; ticket_l = 0; }
    if (tid == 121) ((volatile float*)pad_l)[0] = 0.f;   // keep pad_l allocated

    __syncthreads();   // x_l + control ready

    // ---- encoder: in-lane rank-1 layer1 + 2 MFMAs; wave wv owns t-tile wv ----
    {
        float e1c[16], e1bc[16];
        #pragma unroll
        for (int kc = 0; kc < 2; ++kc)
            #pragma unroll
            for (int jj = 0; jj < 8; ++jj) {
                const int f = kc * 32 + (jj >> 2) * 16 + quad * 4 + (jj & 3);
                e1c[kc * 8 + jj] = e1w[f];
                e1bc[kc * 8 + jj] = e1b[f];
            }
        short8v E2A[2];   // A[m=d(col<8)][k=h feature, permuted]
        #pragma unroll
        for (int kc = 0; kc < 2; ++kc)
            #pragma unroll
            for (int jj = 0; jj < 8; ++jj)
                E2A[kc][jj] = (short)(col < 8
                    ? bfr(e2w[(kc * 32 + (jj >> 2) * 16 + quad * 4 + (jj & 3)) * 8 + col]) : 0);
        float e2bc[4];
        #pragma unroll
        for (int r = 0; r < 4; ++r) e2bc[r] = (quad < 2) ? e2b[quad * 4 + r] : 0.f;

        const int tbase = wv * 16;
        #pragma unroll 1
        for (int nn = 0; nn < 16; ++nn) {
            const float xs = x_l[nn * 130 + tbase + col];
            short8v eB[2];
            #pragma unroll
            for (int kc = 0; kc < 2; ++kc)
                #pragma unroll
                for (int jj = 0; jj < 8; ++jj)
                    eB[kc][jj] = bft(fmaxf(fmaf(xs, e1c[kc * 8 + jj], e1bc[kc * 8 + jj]), 0.f));
            f32x4 d = MFMA32(E2A[0], eB[0], z4);
            d = MFMA32(E2A[1], eB[1], d);
            if (quad < 2) {
                #pragma unroll
                for (int r = 0; r < 4; ++r)
                    enc_l[(tbase + col) * 128 + nn * 8 + quad * 4 + r] = bfr(ftanh(d[r] + e2bc[r]));
            }
        }
    }
    __syncthreads();   // enc_l ready; last block-wide barrier until epilogue

    if (wv == 0) {
        // =========================== SCANNER ===========================
        short8v A2f[16];   // A2f[2d+h]: out j = h*16+quad*4+r, k=i (permuted)
        #pragma unroll
        for (int mt = 0; mt < 16; ++mt)
            #pragma unroll
            for (int jj = 0; jj < 8; ++jj)
                A2f[mt][jj] = (short)bfr(
                    A[((jj >> 2) * 16 + quad * 4 + (jj & 3)) * 256 + (mt >> 1) * 32 + (mt & 1) * 16 + col]);

        // tmp state in f32, permuted in-lane layout: tmpf[jj] = tmp[feat(jj)]
        float tmpf[8];
        #pragma unroll
        for (int jj = 0; jj < 8; ++jj)
            tmpf[jj] = initw[(jj >> 2) * 16 + quad * 4 + (jj & 3)];

        asm volatile("s_setprio 2");   // win SIMD0 VALU arbitration

        short8v e8c = *(const short8v*)&enc_l[0 * 128 + col * 8];  // enc[0] for t=1

        #pragma unroll 1
        for (int t = 0; t < TT; ++t) {
            if (t > 0) {
                // prefetch enc[t] (used at t+1); waited only at e8c=e8n
                const short8v e8n = *(const short8v*)&enc_l[t * 128 + col * 8];
                float ev[8];
                #pragma unroll
                for (int d = 0; d < 8; ++d) ev[d] = bf2f((unsigned short)e8c[d]);

                // B-fold: B_d[k,col] = bf16(ev[d]*tmpf[k]) (R7-verified map).
                // All 8 B's prepped up front, off the MFMA critical path.
                int4v Bu[8];
                #pragma unroll
                for (int d = 0; d < 8; ++d)
                    #pragma unroll
                    for (int k = 0; k < 4; ++k)
                        Bu[d][k] = pk2(ev[d] * tmpf[2 * k + 1], ev[d] * tmpf[2 * k]);

                // 16 INDEPENDENT MFMAs (no chains, no between-group reduction
                // needed -- compiler's natural 8+8 split is now ~free).
                f32x4 acc0[8], acc1[8];
                #pragma unroll
                for (int d = 0; d < 8; ++d) {
                    acc0[d] = MFMA32(A2f[2 * d],     *(const short8v*)&Bu[d], z4);
                    acc1[d] = MFMA32(A2f[2 * d + 1], *(const short8v*)&Bu[d], z4);
                }
                // d-sum: plain f32 partial-sum trees (56 adds total).
                #pragma unroll
                for (int r = 0; r < 4; ++r) {
                    tmpf[r] = ((acc0[0][r] + acc0[1][r]) + (acc0[2][r] + acc0[3][r]))
                            + ((acc0[4][r] + acc0[5][r]) + (acc0[6][r] + acc0[7][r]));
                    tmpf[4 + r] = ((acc1[0][r] + acc1[1][r]) + (acc1[2][r] + acc1[3][r]))
                                + ((acc1[4][r] + acc1[5][r]) + (acc1[6][r] + acc1[7][r]));
                }
                e8c = e8n;
            }
            // ring pack (off critical path): bf16-truncate pairs via v_perm
            int4v rp;
            #pragma unroll
            for (int k = 0; k < 4; ++k)
                rp[k] = pk2(tmpf[2 * k + 1], tmpf[2 * k]);
            ring_l[t & (RING - 1)][lane] = *(const short8v*)&rp;
            if ((t & 3) == 3) {
                // publish every 4 steps: the lgkmcnt(0) drain here also waits
                // the enc prefetch, so amortize it (R4/R6 lesson).
                __threadfence_block();                      // commit ring writes
                if (lane == 0) *(volatile int*)&head_l = t + 1;
            }
            if ((t & 7) == 7 && t >= RING - 1 && t < 120) {
                // next 8 writes hit slots of items t+1-RING..t+8-RING:
                // need min(prog) >= t+9-RING
                const int need = t + 9 - RING;
                while (true) {
                    int p = (lane < 7) ? *(volatile int*)&prog_l[lane] : (1 << 30);
                    #pragma unroll
                    for (int s = 1; s < 64; s <<= 1) {
                        const int q = __shfl_xor(p, s, 64);
                        p = (q < p) ? q : p;
                    }
                    if (p >= need) break;
                    __builtin_amdgcn_s_sleep(4);
                }
            }
        }
        if (lane < 16) part_l[0][lane] = 0.f;
    } else if (wv == 4) {
        // Wave 4 shares SIMD0 with the scanner: idle it so its phi MFMAs /
        // VALU bursts never steal the serial chain's pipes. Tickets
        // redistribute to the 6 consumers on SIMD1-3 automatically.
        if (lane < 16) part_l[4][lane] = 0.f;
    } else {
        // ========================== CONSUMERS ==========================
        short8v W1f[4];    // h1 out = mt*16+col, k = th feature (permuted)
        #pragma unroll
        for (int mt = 0; mt < 4; ++mt)
            #pragma unroll
            for (int jj = 0; jj < 8; ++jj)
                W1f[mt][jj] = (short)bfr(n1w[((jj >> 2) * 16 + quad * 4 + (jj & 3)) * 64 + mt * 16 + col]);
        short8v W2f[4][2];
        #pragma unroll
        for (int mt = 0; mt < 4; ++mt)
            #pragma unroll
            for (int kb = 0; kb < 2; ++kb)
                #pragma unroll
                for (int jj = 0; jj < 8; ++jj)
                    W2f[mt][kb][jj] = (short)bfr(
                        n2w[(kb * 32 + (jj >> 2) * 16 + quad * 4 + (jj & 3)) * 64 + mt * 16 + col]);
        short8v Whf[3][2]; // 0=mu,1=sig,2=alpha; out m = head idx (col<10)
        #pragma unroll
        for (int mt = 0; mt < 3; ++mt) {
            const float* Wh = (mt == 0) ? muw : (mt == 1) ? sgw : alw;
            #pragma unroll
            for (int kb = 0; kb < 2; ++kb)
                #pragma unroll
                for (int jj = 0; jj < 8; ++jj)
                    Whf[mt][kb][jj] = (short)(col < 10
                        ? bfr(Wh[(kb * 32 + (jj >> 2) * 16 + quad * 4 + (jj & 3)) * 10 + col]) : 0);
        }

        float res2 = 0.f;
        const float CST = 0.91893853320467274f;
        const int c = wv - 1;

        int t;
        if (lane == 0) { t = atomicAdd(&ticket_l, 1); *(volatile int*)&prog_l[c] = t; }
        t = __shfl(t, 0, 64);

        while (t < TT) {
            // ACQUIRE: orders the ring read after the observed head bump,
            // in compiler and HW, without an all-memory asm clobber.
            while (__hip_atomic_load(&head_l, __ATOMIC_ACQUIRE,
                                     __HIP_MEMORY_SCOPE_WORKGROUP) <= t)
                __builtin_amdgcn_s_sleep(1);
            const short8v tf = ring_l[t & (RING - 1)][lane];
            __threadfence_block();           // ring read complete before prog bump
            int tn;
            if (lane == 0) { tn = atomicAdd(&ticket_l, 1); *(volatile int*)&prog_l[c] = tn; }
            tn = __shfl(tn, 0, 64);

            short8v thB;
            #pragma unroll
            for (int jj = 0; jj < 8; ++jj)
                thB[jj] = bft(ftanh(bf2f((unsigned short)tf[jj])));

            // h1 = relu(W1^T @ th + b1)   (bias as C operand)
            short8v h1B[2];
            #pragma unroll
            for (int mt = 0; mt < 4; ++mt) {
                const f32x4 cc = *(const f32x4*)&n1b_l[mt * 16 + quad * 4];
                const f32x4 d = MFMA32(W1f[mt], thB, cc);
                #pragma unroll
                for (int r = 0; r < 4; ++r)
                    h1B[mt >> 1][(mt & 1) * 4 + r] = bft(fmaxf(d[r], 0.f));
            }
            // h2 = relu(W2^T @ h1 + b2)
            short8v h2B[2];
            #pragma unroll
            for (int mt = 0; mt < 4; ++mt) {
                const f32x4 cc = *(const f32x4*)&n2b_l[mt * 16 + quad * 4];
                f32x4 d = MFMA32(W2f[mt][0], h1B[0], cc);
                d = MFMA32(W2f[mt][1], h1B[1], d);
                #pragma unroll
                for (int r = 0; r < 4; ++r)
                    h2B[mt >> 1][(mt & 1) * 4 + r] = bft(fmaxf(d[r], 0.f));
            }
            // heads; lane holds heads quad*4+r for sample col
            f32x4 hd[3];
            #pragma unroll
            for (int mt = 0; mt < 3; ++mt) {
                const f32x4 cc = *(const f32x4*)&hb_l[mt * 16 + quad * 4];
                f32x4 d = MFMA32(Whf[mt][0], h2B[0], cc);
                hd[mt] = MFMA32(Whf[mt][1], h2B[1], d);
            }
            // no-max logsumexp (terms O(1); underflow->0 == reference's 0)
            const float xt = x_l[col * 130 + t];
            float s1 = 0.f, s2 = 0.f;
            #pragma unroll
            for (int r = 0; r < 4; ++r) {
                const bool valid = (quad * 4 + r) < 10;
                const float mu = hd[0][r], sg = hd[1][r], la = hd[2][r];
                const float e1t = __expf(la);
                const float z = (xt - mu) * __expf(-sg);
                const float e2t = __expf(la - sg - fmaf(0.5f * z, z, CST));
                s1 += valid ? e1t : 0.f;
                s2 += valid ? e2t : 0.f;
            }
            s1 += __shfl_xor(s1, 16, 64);  s2 += __shfl_xor(s2, 16, 64);
            s1 += __shfl_xor(s1, 32, 64);  s2 += __shfl_xor(s2, 32, 64);
            res2 += __log2f(s2) - __log2f(s1);

            t = tn;
        }
        if (lane == 0) *(volatile int*)&prog_l[c] = 1 << 30;
        if (lane < 16) part_l[wv][lane] = res2;   // uniform across quads
    }

    __syncthreads();
    if (tid < 16) {
        float s = 0.f;
        #pragma unroll
        for (int w = 0; w < 8; ++w) s += part_l[w][tid];
        out[n0 + tid] = exp2f(s);
    }
}

extern "C" void kernel_launch(void* const* d_in, const int* in_sizes, int n_in,
                              void* d_out, int out_size, void* d_ws, size_t ws_size,
                              hipStream_t stream) {
    wfa_kernel<<<dim3(NN / 16), dim3(512), 0, stream>>>(
        (const float*)d_in[0],  (const float*)d_in[1],  (const float*)d_in[2],
        (const float*)d_in[3],  (const float*)d_in[4],  (const float*)d_in[5],
        (const float*)d_in[6],  (const float*)d_in[7],  (const float*)d_in[8],
        (const float*)d_in[9],  (const float*)d_in[10], (const float*)d_in[11],
        (const float*)d_in[12], (const float*)d_in[13], (const float*)d_in[14],
        (const float*)d_in[15], (const float*)d_in[16], (float*)d_out);
}

// Round 10
// 151.709 us; speedup vs baseline: 1.0688x; 1.0688x over previous
//
#include <hip/hip_runtime.h>

#define DEV __device__ __forceinline__

typedef __attribute__((ext_vector_type(8))) short short8v;
typedef __attribute__((ext_vector_type(4))) float f32x4;
typedef __attribute__((ext_vector_type(4))) int int4v;

DEV unsigned short bfr(float f) {                 // fp32 -> bf16 RNE (weights)
    unsigned u = __float_as_uint(f);
    return (unsigned short)((u + 0x7fffu + ((u >> 16) & 1u)) >> 16);
}
DEV short bft(float f) { return (short)(__float_as_uint(f) >> 16); } // truncate (activations)
DEV float bf2f(unsigned short h) { return __uint_as_float(((unsigned)h) << 16); }
DEV float frcp(float x) { return __builtin_amdgcn_rcpf(x); }
DEV float ftanh(float x) { float e = __expf(2.0f * x); return 1.0f - 2.0f * frcp(e + 1.0f); }

constexpr int NN = 4096, TT = 128, RING = 32;
#define MFMA32(a, b, c) __builtin_amdgcn_mfma_f32_16x16x32_bf16(a, b, c, 0, 0, 0)

// Lock-free producer/consumer, 512 threads = R6 base (best, 63.2us), with the
// scanner step body replaced by ONE pure-register inline-asm block.
// R9 POST-MORTEM: seven source-level dataflows all compiled to the same
// {8 MFMA, VALU, 8 MFMA, VALU} shape (VGPR pinned at 88); step stuck at
// ~1190cyc vs ~500 instruction floor => ~600cyc = two MFMA-latency->VALU
// round trips the scheduler refuses to remove. Per R8 pre-commitment:
// inline-asm. The block emits verbatim: 8 ev-unpacks, 16 back-to-back
// independent MFMAs (D in hard-clobbered v40-v103), 2x s_nop 7, then the
// 64-op reduction reading D oldest-first (D[0] read 16+ issues after its
// write; D[15] read ~112cyc after issue -> no hazard, no lambda stall),
// 4x v_perm bf16-pack. LDS ops / fences / poll stay in C: no "memory"
// clobber needed (R2 lesson), no asm-ds_read hazards (rule #18).
// Numerics: same truncate-pack; d-sum association changes (8-deep per
// output vs 4+4) -- prior association changes all passed absmax.
// R1-R3 LESSON: 512 threads only. R6 kept: publish/4, poll/8, wave-4 idle,
// LDS pad >80KB (1 blk/CU => 256-VGPR budget; clobbers push VGPR >=120).

__global__ __launch_bounds__(512) __attribute__((amdgpu_waves_per_eu(2)))
void wfa_kernel(
    const float* __restrict__ x,
    const float* __restrict__ e1w, const float* __restrict__ e1b,
    const float* __restrict__ e2w, const float* __restrict__ e2b,
    const float* __restrict__ A,
    const float* __restrict__ initw,
    const float* __restrict__ n1w, const float* __restrict__ n1b,
    const float* __restrict__ n2w, const float* __restrict__ n2b,
    const float* __restrict__ muw, const float* __restrict__ mub,
    const float* __restrict__ sgw, const float* __restrict__ sgb,
    const float* __restrict__ alw, const float* __restrict__ alb,
    float* __restrict__ out)
{
    __shared__ __align__(16) unsigned short enc_l[TT * 128];  // [t][n*8+d] bf16, 32KB
    __shared__ __align__(16) float x_l[16 * 130];             // [n][t]
    __shared__ __align__(16) short8v ring_l[RING][64];        // tmp frags, 32KB
    __shared__ __align__(16) float n1b_l[64], n2b_l[64], hb_l[48];
    __shared__ float part_l[8][16];
    __shared__ float pad_l[2048];   // 8KB pad: LDS >80KB => 1 blk/CU
                                    // => 256-VGPR budget for the asm block
    __shared__ int head_l;     // items published by scanner
    __shared__ int ticket_l;   // next item index to hand out
    __shared__ int prog_l[7];  // per-consumer: all my ring reads < prog are done

    const int tid = threadIdx.x;
    const int wv = tid >> 6, lane = tid & 63;
    const int quad = lane >> 4, col = lane & 15;
    const int n0 = blockIdx.x * 16;
    const f32x4 z4 = {0.f, 0.f, 0.f, 0.f};

    // ---- stage x + biases + control ----
    for (int i = tid; i < 16 * TT; i += 512)
        x_l[(i >> 7) * 130 + (i & 127)] = x[(n0 + (i >> 7)) * TT + (i & 127)];
    if (tid < 64) { n1b_l[tid] = n1b[tid]; n2b_l[tid] = n2b[tid]; }
    if (tid >= 64 && tid < 112) {
        const int i = tid - 64, mt = i >> 4, k = i & 15;
        hb_l[i] = (k < 10) ? ((mt == 0) ? mub[k] : (mt == 1) ? sgb[k] : alb[k]) : 0.f;
    }
    // prog slot 3 belongs to wave 4, which is idled: park at +inf
    if (tid >= 112 && tid < 119) prog_l[tid - 112] = (tid == 115) ? (1 << 30) : 0;
    if (tid == 120) { head_l = 0; ticket_l = 0; }
    if (tid == 121) ((volatile float*)pad_l)[0] = 0.f;   // keep pad_l allocated

    __syncthreads();   // x_l + control ready

    // ---- encoder: in-lane rank-1 layer1 + 2 MFMAs; wave wv owns t-tile wv ----
    {
        float e1c[16], e1bc[16];
        #pragma unroll
        for (int kc = 0; kc < 2; ++kc)
            #pragma unroll
            for (int jj = 0; jj < 8; ++jj) {
                const int f = kc * 32 + (jj >> 2) * 16 + quad * 4 + (jj & 3);
                e1c[kc * 8 + jj] = e1w[f];
                e1bc[kc * 8 + jj] = e1b[f];
            }
        short8v E2A[2];   // A[m=d(col<8)][k=h feature, permuted]
        #pragma unroll
        for (int kc = 0; kc < 2; ++kc)
            #pragma unroll
            for (int jj = 0; jj < 8; ++jj)
                E2A[kc][jj] = (short)(col < 8
                    ? bfr(e2w[(kc * 32 + (jj >> 2) * 16 + quad * 4 + (jj & 3)) * 8 + col]) : 0);
        float e2bc[4];
        #pragma unroll
        for (int r = 0; r < 4; ++r) e2bc[r] = (quad < 2) ? e2b[quad * 4 + r] : 0.f;

        const int tbase = wv * 16;
        #pragma unroll 1
        for (int nn = 0; nn < 16; ++nn) {
            const float xs = x_l[nn * 130 + tbase + col];
            short8v eB[2];
            #pragma unroll
            for (int kc = 0; kc < 2; ++kc)
                #pragma unroll
                for (int jj = 0; jj < 8; ++jj)
                    eB[kc][jj] = bft(fmaxf(fmaf(xs, e1c[kc * 8 + jj], e1bc[kc * 8 + jj]), 0.f));
            f32x4 d = MFMA32(E2A[0], eB[0], z4);
            d = MFMA32(E2A[1], eB[1], d);
            if (quad < 2) {
                #pragma unroll
                for (int r = 0; r < 4; ++r)
                    enc_l[(tbase + col) * 128 + nn * 8 + quad * 4 + r] = bfr(ftanh(d[r] + e2bc[r]));
            }
        }
    }
    __syncthreads();   // enc_l ready; last block-wide barrier until epilogue

    if (wv == 0) {
        // =========================== SCANNER ===========================
        short8v A2f[16];   // out m=mt*16+col -> d=mt>>1, j-half=mt&1; k=i (permuted)
        #pragma unroll
        for (int mt = 0; mt < 16; ++mt)
            #pragma unroll
            for (int jj = 0; jj < 8; ++jj)
                A2f[mt][jj] = (short)bfr(
                    A[((jj >> 2) * 16 + quad * 4 + (jj & 3)) * 256 + (mt >> 1) * 32 + (mt & 1) * 16 + col]);

        short8v tmpB;
        #pragma unroll
        for (int jj = 0; jj < 8; ++jj)
            tmpB[jj] = (short)bfr(initw[(jj >> 2) * 16 + quad * 4 + (jj & 3)]);

        asm volatile("s_setprio 2");   // win SIMD0 VALU arbitration

        const int sel = 0x07060302;    // v_perm selector: {hi16(src0),hi16(src1)}
        int4v e8c = *(const int4v*)&enc_l[0 * 128 + col * 8];  // enc[0] for t=1

        #pragma unroll 1
        for (int t = 0; t < TT; ++t) {
            if (t > 0) {
                // prefetch enc[t] (used at t+1); waited only at e8c=e8n
                const int4v e8n = *(const int4v*)&enc_l[t * 128 + col * 8];
                int o0, o1, o2, o3;
                // Pure-register step: ev-unpack, 16 back-to-back MFMAs
                // (D=v40..v103), nops, oldest-first reduction (acc=v112..119),
                // bf16 truncate-pack. nt[h*4+r] = sum_d ev[d]*D[2d+h][r];
                // D[m] reg base = 40+4m; ev[d] = v104+d (d-sum ascending).
                asm volatile(
                    "v_lshlrev_b32 v104, 16, %[e0]\n\t"
                    "v_and_b32 v105, 0xffff0000, %[e0]\n\t"
                    "v_lshlrev_b32 v106, 16, %[e1]\n\t"
                    "v_and_b32 v107, 0xffff0000, %[e1]\n\t"
                    "v_lshlrev_b32 v108, 16, %[e2]\n\t"
                    "v_and_b32 v109, 0xffff0000, %[e2]\n\t"
                    "v_lshlrev_b32 v110, 16, %[e3]\n\t"
                    "v_and_b32 v111, 0xffff0000, %[e3]\n\t"
                    "v_mfma_f32_16x16x32_bf16 v[40:43], %[a0], %[tb], 0\n\t"
                    "v_mfma_f32_16x16x32_bf16 v[44:47], %[a1], %[tb], 0\n\t"
                    "v_mfma_f32_16x16x32_bf16 v[48:51], %[a2], %[tb], 0\n\t"
                    "v_mfma_f32_16x16x32_bf16 v[52:55], %[a3], %[tb], 0\n\t"
                    "v_mfma_f32_16x16x32_bf16 v[56:59], %[a4], %[tb], 0\n\t"
                    "v_mfma_f32_16x16x32_bf16 v[60:63], %[a5], %[tb], 0\n\t"
                    "v_mfma_f32_16x16x32_bf16 v[64:67], %[a6], %[tb], 0\n\t"
                    "v_mfma_f32_16x16x32_bf16 v[68:71], %[a7], %[tb], 0\n\t"
                    "v_mfma_f32_16x16x32_bf16 v[72:75], %[a8], %[tb], 0\n\t"
                    "v_mfma_f32_16x16x32_bf16 v[76:79], %[a9], %[tb], 0\n\t"
                    "v_mfma_f32_16x16x32_bf16 v[80:83], %[a10], %[tb], 0\n\t"
                    "v_mfma_f32_16x16x32_bf16 v[84:87], %[a11], %[tb], 0\n\t"
                    "v_mfma_f32_16x16x32_bf16 v[88:91], %[a12], %[tb], 0\n\t"
                    "v_mfma_f32_16x16x32_bf16 v[92:95], %[a13], %[tb], 0\n\t"
                    "v_mfma_f32_16x16x32_bf16 v[96:99], %[a14], %[tb], 0\n\t"
                    "v_mfma_f32_16x16x32_bf16 v[100:103], %[a15], %[tb], 0\n\t"
                    "s_nop 7\n\t"
                    "s_nop 7\n\t"
                    "v_mul_f32 v112, v104, v40\n\t"
                    "v_mul_f32 v113, v104, v41\n\t"
                    "v_mul_f32 v114, v104, v42\n\t"
                    "v_mul_f32 v115, v104, v43\n\t"
                    "v_mul_f32 v116, v104, v44\n\t"
                    "v_mul_f32 v117, v104, v45\n\t"
                    "v_mul_f32 v118, v104, v46\n\t"
                    "v_mul_f32 v119, v104, v47\n\t"
                    "v_fmac_f32 v112, v105, v48\n\t"
                    "v_fmac_f32 v113, v105, v49\n\t"
                    "v_fmac_f32 v114, v105, v50\n\t"
                    "v_fmac_f32 v115, v105, v51\n\t"
                    "v_fmac_f32 v116, v105, v52\n\t"
                    "v_fmac_f32 v117, v105, v53\n\t"
                    "v_fmac_f32 v118, v105, v54\n\t"
                    "v_fmac_f32 v119, v105, v55\n\t"
                    "v_fmac_f32 v112, v106, v56\n\t"
                    "v_fmac_f32 v113, v106, v57\n\t"
                    "v_fmac_f32 v114, v106, v58\n\t"
                    "v_fmac_f32 v115, v106, v59\n\t"
                    "v_fmac_f32 v116, v106, v60\n\t"
                    "v_fmac_f32 v117, v106, v61\n\t"
                    "v_fmac_f32 v118, v106, v62\n\t"
                    "v_fmac_f32 v119, v106, v63\n\t"
                    "v_fmac_f32 v112, v107, v64\n\t"
                    "v_fmac_f32 v113, v107, v65\n\t"
                    "v_fmac_f32 v114, v107, v66\n\t"
                    "v_fmac_f32 v115, v107, v67\n\t"
                    "v_fmac_f32 v116, v107, v68\n\t"
                    "v_fmac_f32 v117, v107, v69\n\t"
                    "v_fmac_f32 v118, v107, v70\n\t"
                    "v_fmac_f32 v119, v107, v71\n\t"
                    "v_fmac_f32 v112, v108, v72\n\t"
                    "v_fmac_f32 v113, v108, v73\n\t"
                    "v_fmac_f32 v114, v108, v74\n\t"
                    "v_fmac_f32 v115, v108, v75\n\t"
                    "v_fmac_f32 v116, v108, v76\n\t"
                    "v_fmac_f32 v117, v108, v77\n\t"
                    "v_fmac_f32 v118, v108, v78\n\t"
                    "v_fmac_f32 v119, v108, v79\n\t"
                    "v_fmac_f32 v112, v109, v80\n\t"
                    "v_fmac_f32 v113, v109, v81\n\t"
                    "v_fmac_f32 v114, v109, v82\n\t"
                    "v_fmac_f32 v115, v109, v83\n\t"
                    "v_fmac_f32 v116, v109, v84\n\t"
                    "v_fmac_f32 v117, v109, v85\n\t"
                    "v_fmac_f32 v118, v109, v86\n\t"
                    "v_fmac_f32 v119, v109, v87\n\t"
                    "v_fmac_f32 v112, v110, v88\n\t"
                    "v_fmac_f32 v113, v110, v89\n\t"
                    "v_fmac_f32 v114, v110, v90\n\t"
                    "v_fmac_f32 v115, v110, v91\n\t"
                    "v_fmac_f32 v116, v110, v92\n\t"
                    "v_fmac_f32 v117, v110, v93\n\t"
                    "v_fmac_f32 v118, v110, v94\n\t"
                    "v_fmac_f32 v119, v110, v95\n\t"
                    "v_fmac_f32 v112, v111, v96\n\t"
                    "v_fmac_f32 v113, v111, v97\n\t"
                    "v_fmac_f32 v114, v111, v98\n\t"
                    "v_fmac_f32 v115, v111, v99\n\t"
                    "v_fmac_f32 v116, v111, v100\n\t"
                    "v_fmac_f32 v117, v111, v101\n\t"
                    "v_fmac_f32 v118, v111, v102\n\t"
                    "v_fmac_f32 v119, v111, v103\n\t"
                    "v_perm_b32 %[o0], v113, v112, %[sl]\n\t"
                    "v_perm_b32 %[o1], v115, v114, %[sl]\n\t"
                    "v_perm_b32 %[o2], v117, v116, %[sl]\n\t"
                    "v_perm_b32 %[o3], v119, v118, %[sl]"
                    : [o0]"=&v"(o0), [o1]"=&v"(o1), [o2]"=&v"(o2), [o3]"=&v"(o3)
                    : [a0]"v"(A2f[0]),  [a1]"v"(A2f[1]),  [a2]"v"(A2f[2]),  [a3]"v"(A2f[3]),
                      [a4]"v"(A2f[4]),  [a5]"v"(A2f[5]),  [a6]"v"(A2f[6]),  [a7]"v"(A2f[7]),
                      [a8]"v"(A2f[8]),  [a9]"v"(A2f[9]),  [a10]"v"(A2f[10]), [a11]"v"(A2f[11]),
                      [a12]"v"(A2f[12]), [a13]"v"(A2f[13]), [a14]"v"(A2f[14]), [a15]"v"(A2f[15]),
                      [tb]"v"(tmpB),
                      [e0]"v"(e8c[0]), [e1]"v"(e8c[1]), [e2]"v"(e8c[2]), [e3]"v"(e8c[3]),
                      [sl]"s"(sel)
                    : "v40","v41","v42","v43","v44","v45","v46","v47",
                      "v48","v49","v50","v51","v52","v53","v54","v55",
                      "v56","v57","v58","v59","v60","v61","v62","v63",
                      "v64","v65","v66","v67","v68","v69","v70","v71",
                      "v72","v73","v74","v75","v76","v77","v78","v79",
                      "v80","v81","v82","v83","v84","v85","v86","v87",
                      "v88","v89","v90","v91","v92","v93","v94","v95",
                      "v96","v97","v98","v99","v100","v101","v102","v103",
                      "v104","v105","v106","v107","v108","v109","v110","v111",
                      "v112","v113","v114","v115","v116","v117","v118","v119");
                int4v ntv;
                ntv[0] = o0; ntv[1] = o1; ntv[2] = o2; ntv[3] = o3;
                tmpB = *(const short8v*)&ntv;
                e8c = e8n;
            }
            ring_l[t & (RING - 1)][lane] = tmpB;
            if ((t & 3) == 3) {
                // publish every 4 steps: the lgkmcnt(0) drain here also waits
                // the enc prefetch, so amortize it (R4/R6 lesson).
                __threadfence_block();                      // commit ring writes
                if (lane == 0) *(volatile int*)&head_l = t + 1;
            }
            if ((t & 7) == 7 && t >= RING - 1 && t < 120) {
                // next 8 writes hit slots of items t+1-RING..t+8-RING:
                // need min(prog) >= t+9-RING
                const int need = t + 9 - RING;
                while (true) {
                    int p = (lane < 7) ? *(volatile int*)&prog_l[lane] : (1 << 30);
                    #pragma unroll
                    for (int s = 1; s < 64; s <<= 1) {
                        const int q = __shfl_xor(p, s, 64);
                        p = (q < p) ? q : p;
                    }
                    if (p >= need) break;
                    __builtin_amdgcn_s_sleep(4);
                }
            }
        }
        if (lane < 16) part_l[0][lane] = 0.f;
    } else if (wv == 4) {
        // Wave 4 shares SIMD0 with the scanner: idle it so its phi MFMAs /
        // VALU bursts never steal the serial chain's pipes. Tickets
        // redistribute to the 6 consumers on SIMD1-3 automatically.
        if (lane < 16) part_l[4][lane] = 0.f;
    } else {
        // ========================== CONSUMERS ==========================
        short8v W1f[4];    // h1 out = mt*16+col, k = th feature (permuted)
        #pragma unroll
        for (int mt = 0; mt < 4; ++mt)
            #pragma unroll
            for (int jj = 0; jj < 8; ++jj)
                W1f[mt][jj] = (short)bfr(n1w[((jj >> 2) * 16 + quad * 4 + (jj & 3)) * 64 + mt * 16 + col]);
        short8v W2f[4][2];
        #pragma unroll
        for (int mt = 0; mt < 4; ++mt)
            #pragma unroll
            for (int kb = 0; kb < 2; ++kb)
                #pragma unroll
                for (int jj = 0; jj < 8; ++jj)
                    W2f[mt][kb][jj] = (short)bfr(
                        n2w[(kb * 32 + (jj >> 2) * 16 + quad * 4 + (jj & 3)) * 64 + mt * 16 + col]);
        short8v Whf[3][2]; // 0=mu,1=sig,2=alpha; out m = head idx (col<10)
        #pragma unroll
        for (int mt = 0; mt < 3; ++mt) {
            const float* Wh = (mt == 0) ? muw : (mt == 1) ? sgw : alw;
            #pragma unroll
            for (int kb = 0; kb < 2; ++kb)
                #pragma unroll
                for (int jj = 0; jj < 8; ++jj)
                    Whf[mt][kb][jj] = (short)(col < 10
                        ? bfr(Wh[(kb * 32 + (jj >> 2) * 16 + quad * 4 + (jj & 3)) * 10 + col]) : 0);
        }

        float res2 = 0.f;
        const float CST = 0.91893853320467274f;
        const int c = wv - 1;

        int t;
        if (lane == 0) { t = atomicAdd(&ticket_l, 1); *(volatile int*)&prog_l[c] = t; }
        t = __shfl(t, 0, 64);

        while (t < TT) {
            // ACQUIRE: orders the ring read after the observed head bump,
            // in compiler and HW, without an all-memory asm clobber.
            while (__hip_atomic_load(&head_l, __ATOMIC_ACQUIRE,
                                     __HIP_MEMORY_SCOPE_WORKGROUP) <= t)
                __builtin_amdgcn_s_sleep(1);
            const short8v tf = ring_l[t & (RING - 1)][lane];
            __threadfence_block();           // ring read complete before prog bump
            int tn;
            if (lane == 0) { tn = atomicAdd(&ticket_l, 1); *(volatile int*)&prog_l[c] = tn; }
            tn = __shfl(tn, 0, 64);

            short8v thB;
            #pragma unroll
            for (int jj = 0; jj < 8; ++jj)
                thB[jj] = bft(ftanh(bf2f((unsigned short)tf[jj])));

            // h1 = relu(W1^T @ th + b1)   (bias as C operand)
            short8v h1B[2];
            #pragma unroll
            for (int mt = 0; mt < 4; ++mt) {
                const f32x4 cc = *(const f32x4*)&n1b_l[mt * 16 + quad * 4];
                const f32x4 d = MFMA32(W1f[mt], thB, cc);
                #pragma unroll
                for (int r = 0; r < 4; ++r)
                    h1B[mt >> 1][(mt & 1) * 4 + r] = bft(fmaxf(d[r], 0.f));
            }
            // h2 = relu(W2^T @ h1 + b2)
            short8v h2B[2];
            #pragma unroll
            for (int mt = 0; mt < 4; ++mt) {
                const f32x4 cc = *(const f32x4*)&n2b_l[mt * 16 + quad * 4];
                f32x4 d = MFMA32(W2f[mt][0], h1B[0], cc);
                d = MFMA32(W2f[mt][1], h1B[1], d);
                #pragma unroll
                for (int r = 0; r < 4; ++r)
                    h2B[mt >> 1][(mt & 1) * 4 + r] = bft(fmaxf(d[r], 0.f));
            }
            // heads; lane holds heads quad*4+r for sample col
            f32x4 hd[3];
            #pragma unroll
            for (int mt = 0; mt < 3; ++mt) {
                const f32x4 cc = *(const f32x4*)&hb_l[mt * 16 + quad * 4];
                f32x4 d = MFMA32(Whf[mt][0], h2B[0], cc);
                hd[mt] = MFMA32(Whf[mt][1], h2B[1], d);
            }
            // no-max logsumexp (terms O(1); underflow->0 == reference's 0)
            const float xt = x_l[col * 130 + t];
            float s1 = 0.f, s2 = 0.f;
            #pragma unroll
            for (int r = 0; r < 4; ++r) {
                const bool valid = (quad * 4 + r) < 10;
                const float mu = hd[0][r], sg = hd[1][r], la = hd[2][r];
                const float e1t = __expf(la);
                const float z = (xt - mu) * __expf(-sg);
                const float e2t = __expf(la - sg - fmaf(0.5f * z, z, CST));
                s1 += valid ? e1t : 0.f;
                s2 += valid ? e2t : 0.f;
            }
            s1 += __shfl_xor(s1, 16, 64);  s2 += __shfl_xor(s2, 16, 64);
            s1 += __shfl_xor(s1, 32, 64);  s2 += __shfl_xor(s2, 32, 64);
            res2 += __log2f(s2) - __log2f(s1);

            t = tn;
        }
        if (lane == 0) *(volatile int*)&prog_l[c] = 1 << 30;
        if (lane < 16) part_l[wv][lane] = res2;   // uniform across quads
    }

    __syncthreads();
    if (tid < 16) {
        float s = 0.f;
        #pragma unroll
        for (int w = 0; w < 8; ++w) s += part_l[w][tid];
        out[n0 + tid] = exp2f(s);
    }
}

extern "C" void kernel_launch(void* const* d_in, const int* in_sizes, int n_in,
                              void* d_out, int out_size, void* d_ws, size_t ws_size,
                              hipStream_t stream) {
    wfa_kernel<<<dim3(NN / 16), dim3(512), 0, stream>>>(
        (const float*)d_in[0],  (const float*)d_in[1],  (const float*)d_in[2],
        (const float*)d_in[3],  (const float*)d_in[4],  (const float*)d_in[5],
        (const float*)d_in[6],  (const float*)d_in[7],  (const float*)d_in[8],
        (const float*)d_in[9],  (const float*)d_in[10], (const float*)d_in[11],
        (const float*)d_in[12], (const float*)d_in[13], (const float*)d_in[14],
        (const float*)d_in[15], (const float*)d_in[16], (float*)d_out);
}

// Round 11
// 144.255 us; speedup vs baseline: 1.1240x; 1.0517x over previous
//
#include <hip/hip_runtime.h>

#define DEV __device__ __forceinline__

typedef __attribute__((ext_vector_type(8))) short short8v;
typedef __attribute__((ext_vector_type(4))) float f32x4;

DEV unsigned short bfr(float f) {                 // fp32 -> bf16 RNE (weights)
    unsigned u = __float_as_uint(f);
    return (unsigned short)((u + 0x7fffu + ((u >> 16) & 1u)) >> 16);
}
DEV short bft(float f) { return (short)(__float_as_uint(f) >> 16); } // truncate (activations)
DEV float bf2f(unsigned short h) { return __uint_as_float(((unsigned)h) << 16); }
DEV float frcp(float x) { return __builtin_amdgcn_rcpf(x); }
DEV float ftanh(float x) { float e = __expf(2.0f * x); return 1.0f - 2.0f * frcp(e + 1.0f); }

constexpr int NN = 4096, TT = 128, RING = 32;
#define MFMA32(a, b, c) __builtin_amdgcn_mfma_f32_16x16x32_bf16(a, b, c, 0, 0, 0)

// ===== SESSION-BEST KERNEL (R6, 63.2us) — verbatim consolidation =====
// R10 POST-MORTEM (final): a verbatim inline-asm step (16 back-to-back
// MFMAs, minimal VALU, no schedulable slack) ran CORRECT but SLOWER
// (73.6us). Combined with R6(1190cyc/step)/R7(1530)/R9(1550)/R10(1390),
// the fitted model: a single wave pays ~55-60cyc PER MFMA at issue
// (multi-wave pipe rate 19cyc does not apply to one wave), VALU is
// additive (not hideable from the same wave), tail ~200cyc. Step floor
// = 16 MFMA (exact minimum: 512 outputs x K=256 / 8192 MACs per instr)
// x ~60 + ~150 VALU + tail ~= 1150-1200cyc -- R6 IS the floor.
// Escapes priced out: multi-wave d-split saves 480cyc but LDS exchange
// costs 350-450; associative-scan rewrite inflates FLOPs 16x (per-sample
// 32x32 chunk products ~26us pipe-bound) with unverified operand layouts.
// Lock-free producer/consumer, 512 threads; scanner with D[16] source
// shape + SGB hints (R8 = this minus SGB/publish4 was +4.7us: keep
// verbatim); publish/4, poll/8, wave-4 idle, LDS pad >80KB.
// R1-R3 LESSON: 512 threads only (1024 => hard 64-VGPR cap => 45MB
// scratch). R2 LESSON: no asm memory clobbers in hot loops.

__global__ __launch_bounds__(512) __attribute__((amdgpu_waves_per_eu(2)))
void wfa_kernel(
    const float* __restrict__ x,
    const float* __restrict__ e1w, const float* __restrict__ e1b,
    const float* __restrict__ e2w, const float* __restrict__ e2b,
    const float* __restrict__ A,
    const float* __restrict__ initw,
    const float* __restrict__ n1w, const float* __restrict__ n1b,
    const float* __restrict__ n2w, const float* __restrict__ n2b,
    const float* __restrict__ muw, const float* __restrict__ mub,
    const float* __restrict__ sgw, const float* __restrict__ sgb,
    const float* __restrict__ alw, const float* __restrict__ alb,
    float* __restrict__ out)
{
    __shared__ __align__(16) unsigned short enc_l[TT * 128];  // [t][n*8+d] bf16, 32KB
    __shared__ __align__(16) float x_l[16 * 130];             // [n][t]
    __shared__ __align__(16) short8v ring_l[RING][64];        // tmp frags, 32KB
    __shared__ __align__(16) float n1b_l[64], n2b_l[64], hb_l[48];
    __shared__ float part_l[8][16];
    __shared__ float pad_l[2048];   // 8KB pad: LDS ~81.5KB > 80KB => 1 blk/CU
    __shared__ int head_l;     // items published by scanner
    __shared__ int ticket_l;   // next item index to hand out
    __shared__ int prog_l[7];  // per-consumer: all my ring reads < prog are done

    const int tid = threadIdx.x;
    const int wv = tid >> 6, lane = tid & 63;
    const int quad = lane >> 4, col = lane & 15;
    const int n0 = blockIdx.x * 16;
    const f32x4 z4 = {0.f, 0.f, 0.f, 0.f};

    // ---- stage x + biases + control ----
    for (int i = tid; i < 16 * TT; i += 512)
        x_l[(i >> 7) * 130 + (i & 127)] = x[(n0 + (i >> 7)) * TT + (i & 127)];
    if (tid < 64) { n1b_l[tid] = n1b[tid]; n2b_l[tid] = n2b[tid]; }
    if (tid >= 64 && tid < 112) {
        const int i = tid - 64, mt = i >> 4, k = i & 15;
        hb_l[i] = (k < 10) ? ((mt == 0) ? mub[k] : (mt == 1) ? sgb[k] : alb[k]) : 0.f;
    }
    // prog slot 3 belongs to wave 4, which is idled this round: park at +inf
    if (tid >= 112 && tid < 119) prog_l[tid - 112] = (tid == 115) ? (1 << 30) : 0;
    if (tid == 120) { head_l = 0; ticket_l = 0; }
    if (tid == 121) ((volatile float*)pad_l)[0] = 0.f;   // keep pad_l allocated

    __syncthreads();   // x_l + control ready

    // ---- encoder: in-lane rank-1 layer1 + 2 MFMAs; wave wv owns t-tile wv ----
    {
        float e1c[16], e1bc[16];
        #pragma unroll
        for (int kc = 0; kc < 2; ++kc)
            #pragma unroll
            for (int jj = 0; jj < 8; ++jj) {
                const int f = kc * 32 + (jj >> 2) * 16 + quad * 4 + (jj & 3);
                e1c[kc * 8 + jj] = e1w[f];
                e1bc[kc * 8 + jj] = e1b[f];
            }
        short8v E2A[2];   // A[m=d(col<8)][k=h feature, permuted]
        #pragma unroll
        for (int kc = 0; kc < 2; ++kc)
            #pragma unroll
            for (int jj = 0; jj < 8; ++jj)
                E2A[kc][jj] = (short)(col < 8
                    ? bfr(e2w[(kc * 32 + (jj >> 2) * 16 + quad * 4 + (jj & 3)) * 8 + col]) : 0);
        float e2bc[4];
        #pragma unroll
        for (int r = 0; r < 4; ++r) e2bc[r] = (quad < 2) ? e2b[quad * 4 + r] : 0.f;

        const int tbase = wv * 16;
        #pragma unroll 1
        for (int nn = 0; nn < 16; ++nn) {
            const float xs = x_l[nn * 130 + tbase + col];
            short8v eB[2];
            #pragma unroll
            for (int kc = 0; kc < 2; ++kc)
                #pragma unroll
                for (int jj = 0; jj < 8; ++jj)
                    eB[kc][jj] = bft(fmaxf(fmaf(xs, e1c[kc * 8 + jj], e1bc[kc * 8 + jj]), 0.f));
            f32x4 d = MFMA32(E2A[0], eB[0], z4);
            d = MFMA32(E2A[1], eB[1], d);
            if (quad < 2) {
                #pragma unroll
                for (int r = 0; r < 4; ++r)
                    enc_l[(tbase + col) * 128 + nn * 8 + quad * 4 + r] = bfr(ftanh(d[r] + e2bc[r]));
            }
        }
    }
    __syncthreads();   // enc_l ready; last block-wide barrier until epilogue

    if (wv == 0) {
        // =========================== SCANNER ===========================
        short8v A2f[16];   // out m=mt*16+col -> d=mt>>1, j-half=mt&1; k=i (permuted)
        #pragma unroll
        for (int mt = 0; mt < 16; ++mt)
            #pragma unroll
            for (int jj = 0; jj < 8; ++jj)
                A2f[mt][jj] = (short)bfr(
                    A[((jj >> 2) * 16 + quad * 4 + (jj & 3)) * 256 + (mt >> 1) * 32 + (mt & 1) * 16 + col]);

        short8v tmpB;
        #pragma unroll
        for (int jj = 0; jj < 8; ++jj)
            tmpB[jj] = (short)bfr(initw[(jj >> 2) * 16 + quad * 4 + (jj & 3)]);

        asm volatile("s_setprio 2");   // win SIMD0 VALU arbitration

        short8v e8c = *(const short8v*)&enc_l[0 * 128 + col * 8];  // enc[0] for t=1

        #pragma unroll 1
        for (int t = 0; t < TT; ++t) {
            if (t > 0) {
                // prefetch enc[t] (used at t+1); waited only at e8c=e8n
                const short8v e8n = *(const short8v*)&enc_l[t * 128 + col * 8];
                float ev[8];
                #pragma unroll
                for (int d = 0; d < 8; ++d) ev[d] = bf2f((unsigned short)e8c[d]);
                f32x4 D[16];
                #pragma unroll
                for (int m = 0; m < 16; ++m) D[m] = MFMA32(A2f[m], tmpB, z4);
                short8v nt;
                #pragma unroll
                for (int h = 0; h < 2; ++h)
                    #pragma unroll
                    for (int r = 0; r < 4; ++r) {
                        // split 4+4 chains: dep tail ~4 fmaf, not 8
                        float sa = ev[0] * D[h][r];
                        float sb = ev[4] * D[8 + h][r];
                        #pragma unroll
                        for (int d = 1; d < 4; ++d) {
                            sa = fmaf(ev[d],     D[2 * d + h][r],     sa);
                            sb = fmaf(ev[d + 4], D[2 * d + 8 + h][r], sb);
                        }
                        nt[h * 4 + r] = bft(sa + sb);
                    }
                // Schedule hints (kept verbatim from the 63.2us build; R8
                // without them was +4.7us -- do not remove).
                __builtin_amdgcn_sched_group_barrier(0x100, 1, 0);  // e8n ds_read first
                __builtin_amdgcn_sched_group_barrier(0x008, 16, 0); // 16 MFMA cluster
                __builtin_amdgcn_sched_group_barrier(0x002, 120, 0); // reduction VALU
                tmpB = nt;
                e8c = e8n;
            }
            ring_l[t & (RING - 1)][lane] = tmpB;
            if ((t & 3) == 3) {
                // publish every 4 steps: the lgkmcnt(0) drain here also waits
                // the enc prefetch, so amortize it (R4 lesson: every-2 cost 10%)
                __threadfence_block();                      // commit ring writes
                if (lane == 0) *(volatile int*)&head_l = t + 1;
            }
            if ((t & 7) == 7 && t >= RING - 1 && t < 120) {
                // next 8 writes hit slots of items t+1-RING..t+8-RING:
                // need min(prog) >= t+9-RING
                const int need = t + 9 - RING;
                while (true) {
                    int p = (lane < 7) ? *(volatile int*)&prog_l[lane] : (1 << 30);
                    #pragma unroll
                    for (int s = 1; s < 64; s <<= 1) {
                        const int q = __shfl_xor(p, s, 64);
                        p = (q < p) ? q : p;
                    }
                    if (p >= need) break;
                    __builtin_amdgcn_s_sleep(4);
                }
            }
        }
        if (lane < 16) part_l[0][lane] = 0.f;
    } else if (wv == 4) {
        // Wave 4 shares SIMD0 with the scanner: idle it so its phi MFMAs /
        // VALU bursts never steal the serial chain's pipes. Tickets
        // redistribute to the 6 consumers on SIMD1-3 automatically.
        if (lane < 16) part_l[4][lane] = 0.f;
    } else {
        // ========================== CONSUMERS ==========================
        short8v W1f[4];    // h1 out = mt*16+col, k = th feature (permuted)
        #pragma unroll
        for (int mt = 0; mt < 4; ++mt)
            #pragma unroll
            for (int jj = 0; jj < 8; ++jj)
                W1f[mt][jj] = (short)bfr(n1w[((jj >> 2) * 16 + quad * 4 + (jj & 3)) * 64 + mt * 16 + col]);
        short8v W2f[4][2];
        #pragma unroll
        for (int mt = 0; mt < 4; ++mt)
            #pragma unroll
            for (int kb = 0; kb < 2; ++kb)
                #pragma unroll
                for (int jj = 0; jj < 8; ++jj)
                    W2f[mt][kb][jj] = (short)bfr(
                        n2w[(kb * 32 + (jj >> 2) * 16 + quad * 4 + (jj & 3)) * 64 + mt * 16 + col]);
        short8v Whf[3][2]; // 0=mu,1=sig,2=alpha; out m = head idx (col<10)
        #pragma unroll
        for (int mt = 0; mt < 3; ++mt) {
            const float* Wh = (mt == 0) ? muw : (mt == 1) ? sgw : alw;
            #pragma unroll
            for (int kb = 0; kb < 2; ++kb)
                #pragma unroll
                for (int jj = 0; jj < 8; ++jj)
                    Whf[mt][kb][jj] = (short)(col < 10
                        ? bfr(Wh[(kb * 32 + (jj >> 2) * 16 + quad * 4 + (jj & 3)) * 10 + col]) : 0);
        }

        float res2 = 0.f;
        const float CST = 0.91893853320467274f;
        const int c = wv - 1;

        int t;
        if (lane == 0) { t = atomicAdd(&ticket_l, 1); *(volatile int*)&prog_l[c] = t; }
        t = __shfl(t, 0, 64);

        while (t < TT) {
            // ACQUIRE: orders the ring read after the observed head bump,
            // in compiler and HW, without an all-memory asm clobber.
            while (__hip_atomic_load(&head_l, __ATOMIC_ACQUIRE,
                                     __HIP_MEMORY_SCOPE_WORKGROUP) <= t)
                __builtin_amdgcn_s_sleep(1);
            const short8v tf = ring_l[t & (RING - 1)][lane];
            __threadfence_block();           // ring read complete before prog bump
            int tn;
            if (lane == 0) { tn = atomicAdd(&ticket_l, 1); *(volatile int*)&prog_l[c] = tn; }
            tn = __shfl(tn, 0, 64);

            short8v thB;
            #pragma unroll
            for (int jj = 0; jj < 8; ++jj)
                thB[jj] = bft(ftanh(bf2f((unsigned short)tf[jj])));

            // h1 = relu(W1^T @ th + b1)   (bias as C operand)
            short8v h1B[2];
            #pragma unroll
            for (int mt = 0; mt < 4; ++mt) {
                const f32x4 cc = *(const f32x4*)&n1b_l[mt * 16 + quad * 4];
                const f32x4 d = MFMA32(W1f[mt], thB, cc);
                #pragma unroll
                for (int r = 0; r < 4; ++r)
                    h1B[mt >> 1][(mt & 1) * 4 + r] = bft(fmaxf(d[r], 0.f));
            }
            // h2 = relu(W2^T @ h1 + b2)
            short8v h2B[2];
            #pragma unroll
            for (int mt = 0; mt < 4; ++mt) {
                const f32x4 cc = *(const f32x4*)&n2b_l[mt * 16 + quad * 4];
                f32x4 d = MFMA32(W2f[mt][0], h1B[0], cc);
                d = MFMA32(W2f[mt][1], h1B[1], d);
                #pragma unroll
                for (int r = 0; r < 4; ++r)
                    h2B[mt >> 1][(mt & 1) * 4 + r] = bft(fmaxf(d[r], 0.f));
            }
            // heads; lane holds heads quad*4+r for sample col
            f32x4 hd[3];
            #pragma unroll
            for (int mt = 0; mt < 3; ++mt) {
                const f32x4 cc = *(const f32x4*)&hb_l[mt * 16 + quad * 4];
                f32x4 d = MFMA32(Whf[mt][0], h2B[0], cc);
                hd[mt] = MFMA32(Whf[mt][1], h2B[1], d);
            }
            // no-max logsumexp (terms O(1); underflow->0 == reference's 0)
            const float xt = x_l[col * 130 + t];
            float s1 = 0.f, s2 = 0.f;
            #pragma unroll
            for (int r = 0; r < 4; ++r) {
                const bool valid = (quad * 4 + r) < 10;
                const float mu = hd[0][r], sg = hd[1][r], la = hd[2][r];
                const float e1t = __expf(la);
                const float z = (xt - mu) * __expf(-sg);
                const float e2t = __expf(la - sg - fmaf(0.5f * z, z, CST));
                s1 += valid ? e1t : 0.f;
                s2 += valid ? e2t : 0.f;
            }
            s1 += __shfl_xor(s1, 16, 64);  s2 += __shfl_xor(s2, 16, 64);
            s1 += __shfl_xor(s1, 32, 64);  s2 += __shfl_xor(s2, 32, 64);
            res2 += __log2f(s2) - __log2f(s1);

            t = tn;
        }
        if (lane == 0) *(volatile int*)&prog_l[c] = 1 << 30;
        if (lane < 16) part_l[wv][lane] = res2;   // uniform across quads
    }

    __syncthreads();
    if (tid < 16) {
        float s = 0.f;
        #pragma unroll
        for (int w = 0; w < 8; ++w) s += part_l[w][tid];
        out[n0 + tid] = exp2f(s);
    }
}

extern "C" void kernel_launch(void* const* d_in, const int* in_sizes, int n_in,
                              void* d_out, int out_size, void* d_ws, size_t ws_size,
                              hipStream_t stream) {
    wfa_kernel<<<dim3(NN / 16), dim3(512), 0, stream>>>(
        (const float*)d_in[0],  (const float*)d_in[1],  (const float*)d_in[2],
        (const float*)d_in[3],  (const float*)d_in[4],  (const float*)d_in[5],
        (const float*)d_in[6],  (const float*)d_in[7],  (const float*)d_in[8],
        (const float*)d_in[9],  (const float*)d_in[10], (const float*)d_in[11],
        (const float*)d_in[12], (const float*)d_in[13], (const float*)d_in[14],
        (const float*)d_in[15], (const float*)d_in[16], (float*)d_out);
}